// Round 4
// baseline (316.806 us; speedup 1.0000x reference)
//
#include <hip/hip_runtime.h>
#include <hip/hip_bf16.h>

// ---------------- problem constants ----------------
#define T_SEQ 8192
#define DMODEL 1024
#define DINNER 2048          // DI
#define NSTATE 16            // DS
#define NCH 128              // scan chunks
#define CL 64                // chunk length (NCH*CL = T_SEQ)

typedef __attribute__((ext_vector_type(8))) short bf16x8;   // 8 bf16 = 4 VGPRs (MFMA A/B frag)
typedef __attribute__((ext_vector_type(4))) float f32x4;    // MFMA C/D frag

__device__ __forceinline__ float bf2f(ushort u) {
  union { unsigned u; float f; } c; c.u = ((unsigned)u) << 16; return c.f;
}
__device__ __forceinline__ ushort f2bf(float f) {
  union { float f; unsigned u; } c; c.f = f;
  unsigned r = c.u + 0x7FFFu + ((c.u >> 16) & 1u);   // RNE
  return (ushort)(r >> 16);
}

#define GLD16(dst, src) __builtin_amdgcn_global_load_lds( \
    (const __attribute__((address_space(1))) void*)(src), \
    (__attribute__((address_space(3))) void*)(dst), 16, 0, 0)

template<int N> __device__ __forceinline__ void waitcnt_vm() {
  asm volatile("s_waitcnt vmcnt(%0)" :: "i"(N) : "memory");
}
#define LGKM0() do { asm volatile("s_waitcnt lgkmcnt(0)" ::: "memory"); \
                     __builtin_amdgcn_sched_barrier(0); } while (0)

// ---------------- prep kernels ----------------
__global__ __launch_bounds__(256) void cast_bf16(const float* __restrict__ in,
                                                 ushort* __restrict__ out, int n4) {
  int i = blockIdx.x * 256 + threadIdx.x;
  if (i < n4) {
    float4 v = ((const float4*)in)[i];
    ushort4 o;
    o.x = f2bf(v.x); o.y = f2bf(v.y); o.z = f2bf(v.z); o.w = f2bf(v.w);
    ((ushort4*)out)[i] = o;
  }
}

// in[R][C] f32 -> out[C][R] bf16   (grid: (C/32, R/32), block (32,8))
__global__ __launch_bounds__(256) void transpose_bf16(const float* __restrict__ in,
                                                      ushort* __restrict__ out, int R, int C) {
  __shared__ float tile[32][33];
  int bx = blockIdx.x * 32;   // C base
  int by = blockIdx.y * 32;   // R base
  int x = threadIdx.x, y = threadIdx.y;
#pragma unroll
  for (int j = 0; j < 32; j += 8)
    tile[y + j][x] = in[(size_t)(by + y + j) * C + bx + x];
  __syncthreads();
#pragma unroll
  for (int j = 0; j < 32; j += 8)
    out[(size_t)(bx + y + j) * R + by + x] = f2bf(tile[x][y + j]);
}

// W_x[2048][33] f32 -> wx48[48][2048] bf16 (transposed, zero-padded rows 33..47)
__global__ __launch_bounds__(256) void wx_transpose_pad(const float* __restrict__ Wx,
                                                        ushort* __restrict__ wxT) {
  int idx = blockIdx.x * 256 + threadIdx.x;   // 48*2048
  int j = idx >> 11;
  int k = idx & 2047;
  wxT[idx] = (j < 33) ? f2bf(Wx[k * 33 + j]) : (ushort)0;
}

// ---------------- per-phase-interleaved GEMM, BM=256 BN=128 BK=64, 3-buf ring --------
// C[M][N] = A[M][K] * B^T, A/B bf16 row-major K-contig.
// 8 waves as 4M x 2N; per-wave 64x64 output (4x4 16x16 frags).
// LDS: A 3 x [256][128B] = 96KB, B 3 x [128][128B] = 48KB -> 144KB, 1 block/CU.
// Swizzle (both sides): byte_in_row ^= (row&7)<<4  -> each ds_read_b128 spreads
// 64 lanes over all eight 16B slots (8 lanes/slot = wave64 minimum).
// Stage plan: during tile t stage tile t+2 (ring slot (t+2)%3, disjoint from the
// two live slots): p1: A rounds 0,1  p2: A rounds 2,3  p3: B round 0  p4: B round 1.
// One vmcnt(6) per tile (end of p4) forces all 6 rounds of t+1 landed (they were
// issued during t-1, 4-7 phases earlier) while keeping t+2's 6 loads in flight.
// Phases: {ds_reads for this quadrant | stage} BAR lgkm(0) prio1 8xMFMA prio0 BAR.
// OUTMODE: 0 = f32 single output; 1 = bf16 split xc/z (col<2048 -> xc else z).
template<int OUTMODE>
__global__ __launch_bounds__(512, 2)
void gemm_pipe(const ushort* __restrict__ A, const ushort* __restrict__ B,
               void* __restrict__ out0, void* __restrict__ out1,
               int N, int K, int nbn) {
  extern __shared__ __align__(16) char smem[];
  char* const smemB = smem + 98304;

  const int tid = threadIdx.x, lane = tid & 63, wid = tid >> 6;
  const int wm = wid >> 1, wn = wid & 1;      // 4M x 2N

  // XCD-bijective swizzle (m204)
  const int nwg = gridDim.x;
  const int q = nwg >> 3, r = nwg & 7;
  const int xcd = blockIdx.x & 7, bidx = blockIdx.x >> 3;
  const int wg = (xcd < r ? xcd * (q + 1) : r * (q + 1) + (xcd - r) * q) + bidx;
  const int mbase = (wg / nbn) * 256;
  const int nbase = (wg % nbn) * 128;
  const int NT = K >> 6;

  // staging source coords (pre-swizzled so linear GLD16 dest + swizzled read match)
  const int srow = tid >> 3;                       // 0..63 within a round
  const int scb = ((tid & 7) << 4) ^ ((srow & 7) << 4);
  const ushort* pa[4];
  const ushort* pb[2];
#pragma unroll
  for (int j = 0; j < 4; ++j) pa[j] = A + (size_t)(mbase + j * 64 + srow) * K + (scb >> 1);
#pragma unroll
  for (int j = 0; j < 2; ++j) pb[j] = B + (size_t)(nbase + j * 64 + srow) * K + (scb >> 1);

#define STA(buf, j, tt) GLD16(smem  + (buf) * 32768 + (j) * 8192 + wid * 1024, pa[j] + (size_t)(tt) * 64)
#define STB(buf, j, tt) GLD16(smemB + (buf) * 16384 + (j) * 8192 + wid * 1024, pb[j] + (size_t)(tt) * 64)

  // ds_read offsets
  const int frow = lane & 15, hh = lane >> 4;
  const int cbk0 = (hh << 4) ^ ((frow & 7) << 4);
  const int cbk1 = (64 + (hh << 4)) ^ ((frow & 7) << 4);
  const int arow0 = (wm * 64 + frow) * 128;        // + mi*2048
  const int brow0 = (wn * 64 + frow) * 128;        // + ni*2048

  f32x4 acc[4][4];
#pragma unroll
  for (int m = 0; m < 4; ++m)
#pragma unroll
    for (int n = 0; n < 4; ++n) acc[m][n] = (f32x4){0.f, 0.f, 0.f, 0.f};

  // prologue: stage tiles 0 and 1 completely (12 loads); force tile 0 landed
#pragma unroll
  for (int tt = 0; tt < 2; ++tt) {
    STA(tt, 0, tt); STA(tt, 1, tt); STA(tt, 2, tt); STA(tt, 3, tt);
    STB(tt, 0, tt); STB(tt, 1, tt);
  }
  waitcnt_vm<6>();
  __builtin_amdgcn_s_barrier();

  int cur = 0;
  for (int t = 0; t < NT; ++t) {
    const char* bA = smem + cur * 32768;
    const char* bB = smemB + cur * 16384;
    const int nxt = cur + 2 - ((cur >= 1) ? 3 : 0);   // (cur+2)%3
    const bool pf = (t + 2 < NT);
    bf16x8 alo[2][2], ahi[2][2], blo[2][2], bhi[2][2];

    // ---- phase 1: Q1 = (m0-1, n0-1); reads a_lo + b_lo; stage A0,A1(t+2)
#pragma unroll
    for (int m = 0; m < 2; ++m) {
      alo[m][0] = *(const bf16x8*)(bA + arow0 + m * 2048 + cbk0);
      alo[m][1] = *(const bf16x8*)(bA + arow0 + m * 2048 + cbk1);
    }
#pragma unroll
    for (int n = 0; n < 2; ++n) {
      blo[n][0] = *(const bf16x8*)(bB + brow0 + n * 2048 + cbk0);
      blo[n][1] = *(const bf16x8*)(bB + brow0 + n * 2048 + cbk1);
    }
    if (pf) { STA(nxt, 0, t + 2); STA(nxt, 1, t + 2); }
    __builtin_amdgcn_s_barrier();
    LGKM0();
    __builtin_amdgcn_s_setprio(1);
#pragma unroll
    for (int m = 0; m < 2; ++m)
#pragma unroll
      for (int n = 0; n < 2; ++n)
#pragma unroll
        for (int kk = 0; kk < 2; ++kk)
          acc[m][n] = __builtin_amdgcn_mfma_f32_16x16x32_bf16(alo[m][kk], blo[n][kk], acc[m][n], 0, 0, 0);
    __builtin_amdgcn_s_setprio(0);
    __builtin_amdgcn_s_barrier();

    // ---- phase 2: Q2 = (m2-3, n0-1); reads a_hi; stage A2,A3(t+2)
#pragma unroll
    for (int m = 0; m < 2; ++m) {
      ahi[m][0] = *(const bf16x8*)(bA + arow0 + (2 + m) * 2048 + cbk0);
      ahi[m][1] = *(const bf16x8*)(bA + arow0 + (2 + m) * 2048 + cbk1);
    }
    if (pf) { STA(nxt, 2, t + 2); STA(nxt, 3, t + 2); }
    __builtin_amdgcn_s_barrier();
    LGKM0();
    __builtin_amdgcn_s_setprio(1);
#pragma unroll
    for (int m = 0; m < 2; ++m)
#pragma unroll
      for (int n = 0; n < 2; ++n)
#pragma unroll
        for (int kk = 0; kk < 2; ++kk)
          acc[2 + m][n] = __builtin_amdgcn_mfma_f32_16x16x32_bf16(ahi[m][kk], blo[n][kk], acc[2 + m][n], 0, 0, 0);
    __builtin_amdgcn_s_setprio(0);
    __builtin_amdgcn_s_barrier();

    // ---- phase 3: Q3 = (m2-3, n2-3); reads b_hi; stage B0(t+2)
#pragma unroll
    for (int n = 0; n < 2; ++n) {
      bhi[n][0] = *(const bf16x8*)(bB + brow0 + (2 + n) * 2048 + cbk0);
      bhi[n][1] = *(const bf16x8*)(bB + brow0 + (2 + n) * 2048 + cbk1);
    }
    if (pf) STB(nxt, 0, t + 2);
    __builtin_amdgcn_s_barrier();
    LGKM0();
    __builtin_amdgcn_s_setprio(1);
#pragma unroll
    for (int m = 0; m < 2; ++m)
#pragma unroll
      for (int n = 0; n < 2; ++n)
#pragma unroll
        for (int kk = 0; kk < 2; ++kk)
          acc[2 + m][2 + n] = __builtin_amdgcn_mfma_f32_16x16x32_bf16(ahi[m][kk], bhi[n][kk], acc[2 + m][2 + n], 0, 0, 0);
    __builtin_amdgcn_s_setprio(0);
    __builtin_amdgcn_s_barrier();

    // ---- phase 4: Q4 = (m0-1, n2-3); no reads (a_lo, b_hi held); stage B1(t+2)
    if (pf) STB(nxt, 1, t + 2);
    __builtin_amdgcn_s_setprio(1);
#pragma unroll
    for (int m = 0; m < 2; ++m)
#pragma unroll
      for (int n = 0; n < 2; ++n)
#pragma unroll
        for (int kk = 0; kk < 2; ++kk)
          acc[m][2 + n] = __builtin_amdgcn_mfma_f32_16x16x32_bf16(alo[m][kk], bhi[n][kk], acc[m][2 + n], 0, 0, 0);
    __builtin_amdgcn_s_setprio(0);
    if (pf) waitcnt_vm<6>(); else waitcnt_vm<0>();
    __builtin_amdgcn_s_barrier();

    cur = cur + 1 - ((cur == 2) ? 3 : 0);
  }

  // epilogue: C/D layout col=lane&15, row=(lane>>4)*4+reg  [m89/m91]
  const int crow0 = mbase + wm * 64 + (lane >> 4) * 4;
  const int ccol0 = nbase + wn * 64 + (lane & 15);
#pragma unroll
  for (int m = 0; m < 4; ++m)
#pragma unroll
    for (int n = 0; n < 4; ++n)
#pragma unroll
      for (int j = 0; j < 4; ++j) {
        int rr = crow0 + m * 16 + j;
        int cc = ccol0 + n * 16;
        float v = acc[m][n][j];
        if (OUTMODE == 0) {
          ((float*)out0)[(size_t)rr * N + cc] = v;
        } else {
          ushort* dst = (cc < 2048) ? (ushort*)out0 : (ushort*)out1;
          int c2 = cc & 2047;
          dst[(size_t)rr * 2048 + c2] = f2bf(v);
        }
      }
#undef STA
#undef STB
}

// ---------------- thin GEMM: xdbl = xs @ W_x (N=48 pad), 4-way split-K ----------------
__global__ __launch_bounds__(256) void gemm_thin(const ushort* __restrict__ A,
                                                 const ushort* __restrict__ Bw,
                                                 float* __restrict__ part) {
  __shared__ __align__(16) ushort sA[128 * 64];   // 16 KB
  __shared__ __align__(16) ushort sB[48 * 64];    // 6 KB
  const int tid = threadIdx.x, lane = tid & 63, wid = tid >> 6;
  const int mbase = blockIdx.x * 128;
  const int kbase = blockIdx.y * 512;
  const int frow = lane & 15, fke = (lane >> 4) * 8;

  f32x4 acc[2][3];
#pragma unroll
  for (int m = 0; m < 2; ++m)
#pragma unroll
    for (int n = 0; n < 3; ++n) acc[m][n] = (f32x4){0.f, 0.f, 0.f, 0.f};

  for (int k0 = 0; k0 < 512; k0 += 64) {
#pragma unroll
    for (int j = 0; j < 4; ++j) {
      int o = tid * 16 + j * 4096;
      int row = o >> 7, ke = ((o >> 4) & 7) * 8;
      GLD16((char*)sA + wid * 1024 + j * 4096,
            A + (size_t)(mbase + row) * DINNER + kbase + k0 + ke);
    }
    for (int i = tid; i < 384; i += 256) {
      int brow = i >> 3, kc = (i & 7) * 8;
      *(bf16x8*)&sB[brow * 64 + kc] = *(const bf16x8*)(Bw + (size_t)brow * DINNER + kbase + k0 + kc);
    }
    __syncthreads();
    bf16x8 af[2][2], bf_[3][2];
#pragma unroll
    for (int m = 0; m < 2; ++m)
#pragma unroll
      for (int ks = 0; ks < 2; ++ks)
        af[m][ks] = *(const bf16x8*)&sA[(wid * 32 + m * 16 + frow) * 64 + ks * 32 + fke];
#pragma unroll
    for (int n = 0; n < 3; ++n)
#pragma unroll
      for (int ks = 0; ks < 2; ++ks)
        bf_[n][ks] = *(const bf16x8*)&sB[(n * 16 + frow) * 64 + ks * 32 + fke];
#pragma unroll
    for (int m = 0; m < 2; ++m)
#pragma unroll
      for (int n = 0; n < 3; ++n)
#pragma unroll
        for (int ks = 0; ks < 2; ++ks)
          acc[m][n] = __builtin_amdgcn_mfma_f32_16x16x32_bf16(af[m][ks], bf_[n][ks], acc[m][n], 0, 0, 0);
    __syncthreads();
  }
  float* po = part + (size_t)blockIdx.y * (T_SEQ * 48);
#pragma unroll
  for (int m = 0; m < 2; ++m)
#pragma unroll
    for (int n = 0; n < 3; ++n)
#pragma unroll
      for (int j = 0; j < 4; ++j) {
        int rr = mbase + wid * 32 + m * 16 + (lane >> 4) * 4 + j;
        int cc = n * 16 + (lane & 15);
        po[(size_t)rr * 48 + cc] = acc[m][n][j];
      }
}

__global__ __launch_bounds__(256) void reduce4(const float* __restrict__ part,
                                               float* __restrict__ xdbl) {
  int i = blockIdx.x * 256 + threadIdx.x;
  const float4* p = (const float4*)part;
  float4 a = p[i], b = p[i + 98304], c = p[i + 2 * 98304], d = p[i + 3 * 98304];
  ((float4*)xdbl)[i] = make_float4(a.x + b.x + c.x + d.x, a.y + b.y + c.y + d.y,
                                   a.z + b.z + c.z + d.z, a.w + b.w + c.w + d.w);
}

// ---------------- depthwise causal conv (DC=4) + silu; xc stride 2048 now ----------------
__global__ __launch_bounds__(256) void conv_silu(const ushort* __restrict__ xc,
                                                 const float* __restrict__ cw,
                                                 const float* __restrict__ cb,
                                                 ushort* __restrict__ xs) {
  int idx = blockIdx.x * 256 + threadIdx.x;   // t*2048 + d
  int t = idx >> 11, d = idx & 2047;
  float4 w = *(const float4*)(cw + d * 4);
  float a = cb[d];
  const float wk[4] = {w.x, w.y, w.z, w.w};
#pragma unroll
  for (int k = 0; k < 4; ++k) {
    int tt = t - 3 + k;
    if (tt >= 0) a += bf2f(xc[(size_t)tt * 2048 + d]) * wk[k];
  }
  float s = a / (1.f + expf(-a));
  xs[idx] = f2bf(s);
}

// ---------------- scan precompute (xdbl stride 48) ----------------
__global__ __launch_bounds__(256) void precompute_k(const float* __restrict__ xdbl,
                                                    const float* __restrict__ A_log,
                                                    float* __restrict__ abar,
                                                    float* __restrict__ bbar,
                                                    float* __restrict__ cc,
                                                    float* __restrict__ dlt) {
  int t = blockIdx.x * 256 + threadIdx.x;
  if (t >= T_SEQ) return;
  const float* r = xdbl + (size_t)t * 48;
  float v = r[0];
  float delta = (v > 20.f) ? v : log1pf(expf(v));
  dlt[t] = delta;
#pragma unroll
  for (int n = 0; n < NSTATE; ++n) {
    float A = -expf(A_log[n]);
    abar[t * 16 + n] = expf(delta * A);
    bbar[t * 16 + n] = delta * r[1 + n];
    cc[t * 16 + n]   = r[17 + n];
  }
}

__global__ __launch_bounds__(256) void chunkprod_k(const float* __restrict__ dlt,
                                                   const float* __restrict__ A_log,
                                                   float* __restrict__ P) {
  int idx = blockIdx.x * 256 + threadIdx.x;
  if (idx >= NCH * NSTATE) return;
  int c = idx >> 4, n = idx & 15;
  float s = 0.f;
  for (int i = 0; i < CL; ++i) s += dlt[c * CL + i];
  P[idx] = expf(-expf(A_log[n]) * s);
}

// ---------------- scan pass 1 ----------------
__global__ __launch_bounds__(256) void scan1(const ushort* __restrict__ xs,
                                             const float* __restrict__ abar,
                                             const float* __restrict__ bbar,
                                             float* __restrict__ hend) {
  int c = blockIdx.x;
  int d = blockIdx.y * 256 + threadIdx.x;
  __shared__ float s_ab[CL * 16], s_bb[CL * 16];
  for (int e = threadIdx.x; e < CL * 16; e += 256) {
    s_ab[e] = abar[(size_t)c * CL * 16 + e];
    s_bb[e] = bbar[(size_t)c * CL * 16 + e];
  }
  __syncthreads();
  float h[16];
#pragma unroll
  for (int n = 0; n < 16; ++n) h[n] = 0.f;
  int tbase = c * CL;
  for (int i = 0; i < CL; ++i) {
    float x = bf2f(xs[(size_t)(tbase + i) * DINNER + d]);
#pragma unroll
    for (int n = 0; n < 16; ++n) h[n] = s_ab[i * 16 + n] * h[n] + s_bb[i * 16 + n] * x;
  }
  float* o = hend + ((size_t)c * DINNER + d) * 16;
#pragma unroll
  for (int qq = 0; qq < 4; ++qq)
    ((float4*)o)[qq] = make_float4(h[4 * qq], h[4 * qq + 1], h[4 * qq + 2], h[4 * qq + 3]);
}

// ---------------- scan pass 2 ----------------
__global__ __launch_bounds__(256) void scan2(const float* __restrict__ hend,
                                             const float* __restrict__ P,
                                             float* __restrict__ hin) {
  int idx = blockIdx.x * 256 + threadIdx.x;
  int n = idx & 15;
  float h = 0.f;
  for (int c = 0; c < NCH; ++c) {
    hin[(size_t)c * (DINNER * 16) + idx] = h;
    h = P[c * 16 + n] * h + hend[(size_t)c * (DINNER * 16) + idx];
  }
}

// ---------------- scan pass 3 (z now contiguous [T][2048]) ----------------
__global__ __launch_bounds__(256) void scan3(const ushort* __restrict__ xs,
                                             const ushort* __restrict__ zb,
                                             const float* __restrict__ abar,
                                             const float* __restrict__ bbar,
                                             const float* __restrict__ cc,
                                             const float* __restrict__ hin,
                                             const float* __restrict__ Dv,
                                             ushort* __restrict__ y) {
  int c = blockIdx.x;
  int d = blockIdx.y * 256 + threadIdx.x;
  __shared__ float s_ab[CL * 16], s_bb[CL * 16], s_cc[CL * 16];
  for (int e = threadIdx.x; e < CL * 16; e += 256) {
    s_ab[e] = abar[(size_t)c * CL * 16 + e];
    s_bb[e] = bbar[(size_t)c * CL * 16 + e];
    s_cc[e] = cc[(size_t)c * CL * 16 + e];
  }
  __syncthreads();
  float h[16];
  const float* hi = hin + ((size_t)c * DINNER + d) * 16;
#pragma unroll
  for (int qq = 0; qq < 4; ++qq) {
    float4 v = ((const float4*)hi)[qq];
    h[4 * qq] = v.x; h[4 * qq + 1] = v.y; h[4 * qq + 2] = v.z; h[4 * qq + 3] = v.w;
  }
  float Dd = Dv[d];
  int tbase = c * CL;
  for (int i = 0; i < CL; ++i) {
    size_t t = tbase + i;
    float x = bf2f(xs[t * DINNER + d]);
    float ys = 0.f;
#pragma unroll
    for (int n = 0; n < 16; ++n) {
      h[n] = s_ab[i * 16 + n] * h[n] + s_bb[i * 16 + n] * x;
      ys += s_cc[i * 16 + n] * h[n];
    }
    float z = bf2f(zb[t * 2048 + d]);
    float yv = (ys + Dd * x) * (z / (1.f + expf(-z)));
    y[t * DINNER + d] = f2bf(yv);
  }
}

// ---------------- launch ----------------
extern "C" void kernel_launch(void* const* d_in, const int* in_sizes, int n_in,
                              void* d_out, int out_size, void* d_ws, size_t ws_size,
                              hipStream_t stream) {
  const float* x      = (const float*)d_in[0];
  const float* W_in   = (const float*)d_in[1];
  const float* conv_w = (const float*)d_in[2];
  const float* conv_b = (const float*)d_in[3];
  const float* W_x    = (const float*)d_in[4];
  const float* A_log  = (const float*)d_in[5];
  const float* Dv     = (const float*)d_in[6];
  const float* W_out  = (const float*)d_in[7];
  float* out = (float*)d_out;

  char* w = (char*)d_ws;
  auto alloc = [&](size_t bytes) { char* p = w; w += (bytes + 255) & ~(size_t)255; return p; };

  ushort* xbf   = (ushort*)alloc((size_t)T_SEQ * DMODEL * 2);
  ushort* winT  = (ushort*)alloc((size_t)4096 * 1024 * 2);
  ushort* woutT = (ushort*)alloc((size_t)1024 * 2048 * 2);
  ushort* wxT   = (ushort*)alloc((size_t)48 * 2048 * 2);
  ushort* xc    = (ushort*)alloc((size_t)T_SEQ * DINNER * 2);   // 33.6 MB
  ushort* zb    = (ushort*)alloc((size_t)T_SEQ * DINNER * 2);   // 33.6 MB
  ushort* xs    = (ushort*)alloc((size_t)T_SEQ * DINNER * 2);
  float*  xdbl  = (float*) alloc((size_t)T_SEQ * 48 * 4);
  float*  parts = (float*) alloc((size_t)4 * T_SEQ * 48 * 4);
  float*  abar  = (float*) alloc((size_t)T_SEQ * 16 * 4);
  float*  bbar  = (float*) alloc((size_t)T_SEQ * 16 * 4);
  float*  ccb   = (float*) alloc((size_t)T_SEQ * 16 * 4);
  float*  dlt   = (float*) alloc((size_t)T_SEQ * 4);
  float*  P     = (float*) alloc((size_t)NCH * 16 * 4);
  float*  hend  = (float*) alloc((size_t)NCH * DINNER * 16 * 4);
  float*  hin   = (float*) alloc((size_t)NCH * DINNER * 16 * 4);
  ushort* ybf   = (ushort*)alloc((size_t)T_SEQ * DINNER * 2);

  auto kg1 = gemm_pipe<1>;
  auto kg3 = gemm_pipe<0>;
  hipFuncSetAttribute(reinterpret_cast<const void*>(kg1),
                      hipFuncAttributeMaxDynamicSharedMemorySize, 147456);
  hipFuncSetAttribute(reinterpret_cast<const void*>(kg3),
                      hipFuncAttributeMaxDynamicSharedMemorySize, 147456);

  // prep
  cast_bf16<<<(T_SEQ * DMODEL / 4 + 255) / 256, 256, 0, stream>>>(x, xbf, T_SEQ * DMODEL / 4);
  transpose_bf16<<<dim3(4096 / 32, 1024 / 32), dim3(32, 8), 0, stream>>>(W_in, winT, 1024, 4096);
  transpose_bf16<<<dim3(1024 / 32, 2048 / 32), dim3(32, 8), 0, stream>>>(W_out, woutT, 2048, 1024);
  wx_transpose_pad<<<(48 * 2048) / 256, 256, 0, stream>>>(W_x, wxT);

  // GEMM1: [xc|z] = x @ W_in (8192x4096, K=1024), bf16 split out; 1024 blocks
  kg1<<<dim3((T_SEQ / 256) * (4096 / 128)), 512, 147456, stream>>>(xbf, winT, xc, zb, 4096, 1024, 4096 / 128);

  // conv + silu
  conv_silu<<<(T_SEQ * DINNER) / 256, 256, 0, stream>>>(xc, conv_w, conv_b, xs);

  // GEMM2: xdbl = xs @ W_x (N=48 pad, split-K 4)
  gemm_thin<<<dim3(T_SEQ / 128, 4), 256, 0, stream>>>(xs, wxT, parts);
  reduce4<<<(T_SEQ * 48 / 4) / 256, 256, 0, stream>>>(parts, xdbl);

  // scan precompute
  precompute_k<<<T_SEQ / 256, 256, 0, stream>>>(xdbl, A_log, abar, bbar, ccb, dlt);
  chunkprod_k<<<(NCH * 16 + 255) / 256, 256, 0, stream>>>(dlt, A_log, P);

  // 3-pass chunked scan
  scan1<<<dim3(NCH, DINNER / 256), 256, 0, stream>>>(xs, abar, bbar, hend);
  scan2<<<(DINNER * 16) / 256, 256, 0, stream>>>(hend, P, hin);
  scan3<<<dim3(NCH, DINNER / 256), 256, 0, stream>>>(xs, zb, abar, bbar, ccb, hin, Dv, ybf);

  // GEMM3: out = y @ W_out (8192x1024, K=2048), f32 out; 256 blocks
  kg3<<<dim3((T_SEQ / 256) * (1024 / 128)), 512, 147456, stream>>>(ybf, woutT, out, nullptr, 1024, 2048, 1024 / 128);
}